// Round 11
// baseline (4499.737 us; speedup 1.0000x reference)
//
#include <hip/hip_runtime.h>
#include <hip/hip_bf16.h>

#define Bb 8
#define Ss 128
#define Hh 1024
#define Vv 32000
#define NROWS (Bb*Ss)   // 1024

typedef __bf16 bf16;
typedef __bf16 v8bf __attribute__((ext_vector_type(8)));
typedef __bf16 v4bf __attribute__((ext_vector_type(4)));
typedef float  f32x4 __attribute__((ext_vector_type(4)));

// Dependency-chain probe: measures per-launch boundary cost. 126 of these
// inserted into the scan chain; delta-dur/126 = B_empty.
__global__ void k_nop() {}

// ---------------------------------------------------------------------------
// Pack row-major f32 W[K][N] -> frag-linear bf16 (validated layout):
//   Wp[((c*(N/16) + s)*64 + l)*8 + e] = W[32c + 8*(l>>4) + e][16s + (l&15)]
// optionally scaling row k by gscale[k & 1023] (LN-gamma fold).
// grid (K/32, N/256), block 256.
// ---------------------------------------------------------------------------
__global__ __launch_bounds__(256) void k_pack2(
    const float* __restrict__ W, bf16* __restrict__ Wp, int N,
    const float* __restrict__ gscale)
{
    __shared__ bf16 lt[32][258];
    const int c = blockIdx.x, n0 = blockIdx.y << 8;
    const int Ns = N >> 4, s0 = n0 >> 4;
    const int tid = threadIdx.x;
    #pragma unroll
    for (int i = 0; i < 8; ++i) {
        int q = (i << 8) + tid;          // 2048 float4 slots = 32 rows x 64
        int kk = q >> 6, nq = q & 63;
        float gs = gscale ? gscale[((c << 5) + kk) & 1023] : 1.0f;
        float4 v = *reinterpret_cast<const float4*>(
            &W[(size_t)((c << 5) + kk) * N + n0 + (nq << 2)]);
        lt[kk][(nq << 2) + 0] = (bf16)(v.x * gs);
        lt[kk][(nq << 2) + 1] = (bf16)(v.y * gs);
        lt[kk][(nq << 2) + 2] = (bf16)(v.z * gs);
        lt[kk][(nq << 2) + 3] = (bf16)(v.w * gs);
    }
    __syncthreads();
    #pragma unroll
    for (int u = 0; u < 4; ++u) {
        int p = (u << 8) + tid;          // 1024 (s,l) pairs
        int s = p >> 6, ll = p & 63;
        v8bf pk;
        #pragma unroll
        for (int e = 0; e < 8; ++e)
            pk[e] = lt[((ll >> 4) << 3) + e][(s << 4) + (ll & 15)];
        *reinterpret_cast<v8bf*>(
            &Wp[((((size_t)c * Ns + s0 + s) << 6) + ll) << 3]) = pk;
    }
}

// cbias[n] = b_sani[n] + sum_k W_sani[k][n] * lnb[k & 1023]. grid 4 x 256.
__global__ __launch_bounds__(256) void k_cbias(
    const float* __restrict__ W, const float* __restrict__ bs,
    const float* __restrict__ lnb, float* __restrict__ cbias)
{
    const int col = blockIdx.x * 256 + threadIdx.x;
    float s = bs[col];
    #pragma unroll 8
    for (int k = 0; k < 2 * Hh; ++k)
        s = fmaf(W[(size_t)k * Hh + col], lnb[k & (Hh - 1)], s);
    cbias[col] = s;
}

// ---------------------------------------------------------------------------
// Generic rows x 1024 GEMM, K=1024 (fp32).
// MODE 0: A-row = emb[labels[row]] (gather), relu, + bf16 mirror out.
// MODE 1: A-row = A[row] (direct), exact gelu.
// ---------------------------------------------------------------------------
template<int MODE>
__global__ __launch_bounds__(256) void k_gemm1024(
    const int* __restrict__ labels, const float* __restrict__ A,
    const float* __restrict__ W, const float* __restrict__ bias,
    float* __restrict__ out, bf16* __restrict__ outb)
{
    __shared__ float Als[16][32];
    const int tid  = threadIdx.x;
    const int jj   = (blockIdx.x << 8) + ((tid & 63) << 2);
    const int rg   = tid >> 6;
    const int row0 = blockIdx.y << 4;
    float acc[4][4] = {};
    for (int k0 = 0; k0 < Hh; k0 += 32) {
        __syncthreads();
        #pragma unroll
        for (int u = 0; u < 2; ++u) {
            int i = (u << 8) + tid;
            int r = i >> 5, kk = i & 31;
            int row = row0 + r;
            size_t base = (MODE == 0) ? (size_t)labels[row] * Hh : (size_t)row * Hh;
            Als[r][kk] = A[base + k0 + kk];
        }
        __syncthreads();
        #pragma unroll 8
        for (int kk = 0; kk < 32; ++kk) {
            const float4 w4 = *reinterpret_cast<const float4*>(&W[(size_t)(k0 + kk) * Hh + jj]);
            #pragma unroll
            for (int i = 0; i < 4; ++i) {
                float a = Als[(rg << 2) + i][kk];
                acc[i][0] = fmaf(a, w4.x, acc[i][0]);
                acc[i][1] = fmaf(a, w4.y, acc[i][1]);
                acc[i][2] = fmaf(a, w4.z, acc[i][2]);
                acc[i][3] = fmaf(a, w4.w, acc[i][3]);
            }
        }
    }
    const float4 b4 = *reinterpret_cast<const float4*>(&bias[jj]);
    #pragma unroll
    for (int i = 0; i < 4; ++i) {
        int row = row0 + (rg << 2) + i;
        float v[4] = {acc[i][0] + b4.x, acc[i][1] + b4.y, acc[i][2] + b4.z, acc[i][3] + b4.w};
        float o[4];
        #pragma unroll
        for (int j = 0; j < 4; ++j) {
            if (MODE == 0) o[j] = fmaxf(v[j], 0.f);
            else           o[j] = 0.5f * v[j] * (1.f + erff(v[j] * 0.70710678f));
        }
        *reinterpret_cast<float4*>(&out[(size_t)row * Hh + jj]) =
            make_float4(o[0], o[1], o[2], o[3]);
        if (MODE == 0) {
            v4bf ob; ob[0] = (bf16)o[0]; ob[1] = (bf16)o[1];
            ob[2] = (bf16)o[2]; ob[3] = (bf16)o[3];
            *reinterpret_cast<v4bf*>(&outb[(size_t)row * Hh + jj]) = ob;
        }
    }
}

// ---------------------------------------------------------------------------
// Fused scan step m (unchanged from R10; == R6 perf). Block 32r x 128c,
// 512 thr, 8 waves, wave 16r x 32c. grid (8, ceil(nt/32), 8).
// C/D map: col=l&15, row=4*(l>>4)+j [validated].
// ---------------------------------------------------------------------------
template<int FIRST>
__global__ __launch_bounds__(512) void k_scan_fused6(
    const bf16* __restrict__ hbA, const float* __restrict__ hfS,
    float* __restrict__ hfD, bf16* __restrict__ hbD,
    const bf16* __restrict__ Wp, const float* __restrict__ cb,
    const float* __restrict__ prtR, float* __restrict__ prtW,
    const float* __restrict__ lng, const float* __restrict__ lnb, int m)
{
    __shared__ float musig[33][2];   // (mu, rs) for rows t0-1 .. t0+31
    __shared__ float ls[32][4][2];
    const int tid = threadIdx.x, l = tid & 63, w = tid >> 6;
    const int wm = w >> 2, wn = w & 3;
    const int lo = l & 15, hi = l >> 4;
    const int bx = blockIdx.x;                 // 0..7 (128-col blocks)
    const int n0 = bx << 7;
    const int t0 = m + 1 + (blockIdx.y << 5);
    const int b  = blockIdx.z;

    if constexpr (!FIRST) {
        if (tid < 264) {
            const int idx = tid >> 3, pr = tid & 7;
            int r = t0 - 1 + idx; if (r > 126) r = 126;
            const float2 v = *reinterpret_cast<const float2*>(
                prtR + (((size_t)(b * Ss + r)) << 4) + (pr << 1));
            float s1 = v.x, s2 = v.y;
            #pragma unroll
            for (int off = 1; off < 8; off <<= 1) {
                s1 += __shfl_xor(s1, off);
                s2 += __shfl_xor(s2, off);
            }
            if (pr == 0) {
                const float mu = s1 * (1.f / Hh);
                const float rs = rsqrtf(s2 * (1.f / Hh) - mu * mu + 1e-5f);
                musig[idx][0] = mu; musig[idx][1] = rs;
            }
        }
        __syncthreads();
    }

    int tA = t0 + (wm << 4) + lo; if (tA > 126) tA = 126;
    const bf16* pA  = hbA + (((size_t)(b * Ss + tA - 1)) << 10) + (hi << 3);
    const bf16* pB0 = Wp + (((size_t)(((bx << 3) + (wn << 1)) << 6) + l) << 3);
    const bf16* pB1 = pB0 + 512;

    float rsA[2] = {1.f, 1.f}, cA[2] = {0.f, 0.f};
    float muE[4] = {0.f, 0.f, 0.f, 0.f}, rsE[4] = {1.f, 1.f, 1.f, 1.f};
    if constexpr (!FIRST) {
        const int ia = tA - t0;
        #pragma unroll
        for (int q = 0; q < 2; ++q) {
            const float mu = musig[ia + q][0], rs = musig[ia + q][1];
            rsA[q] = rs; cA[q] = -mu * rs;
        }
        #pragma unroll
        for (int j = 0; j < 4; ++j) {
            const int ie = (wm << 4) + (hi << 2) + j + 1;   // always <= 32
            muE[j] = musig[ie][0]; rsE[j] = musig[ie][1];
        }
    }

    f32x4 acc0 = {}, acc1 = {};
    uint4 ra0, ra1, ra2, ra3;
    v8bf b00, b01, b10, b11, b20, b21, b30, b31;

#define SLD(i, cc) do {                                                       \
        ra##i = *reinterpret_cast<const uint4*>(pA + ((cc) << 5));            \
        b##i##0 = *reinterpret_cast<const v8bf*>(pB0 + ((size_t)(cc) << 15)); \
        b##i##1 = *reinterpret_cast<const v8bf*>(pB1 + ((size_t)(cc) << 15)); \
    } while (0)
#define SCP(i) do {                                                           \
        v8bf a_;                                                              \
        if constexpr (FIRST) {                                                \
            a_ = *reinterpret_cast<const v8bf*>(&ra##i);                      \
        } else {                                                              \
            const unsigned u_[4] = {ra##i.x, ra##i.y, ra##i.z, ra##i.w};      \
            _Pragma("unroll")                                                 \
            for (int i_ = 0; i_ < 4; ++i_) {                                  \
                float xl_ = __uint_as_float(u_[i_] << 16);                    \
                float xh_ = __uint_as_float(u_[i_] & 0xffff0000u);            \
                a_[2 * i_]     = (bf16)fmaf(xl_, rsel, csel);                 \
                a_[2 * i_ + 1] = (bf16)fmaf(xh_, rsel, csel);                 \
            }                                                                 \
        }                                                                     \
        acc0 = __builtin_amdgcn_mfma_f32_16x16x32_bf16(a_, b##i##0, acc0, 0, 0, 0); \
        acc1 = __builtin_amdgcn_mfma_f32_16x16x32_bf16(a_, b##i##1, acc1, 0, 0, 0); \
    } while (0)

    #pragma unroll
    for (int half = 0; half < 2; ++half) {
        const float rsel = FIRST ? 1.f : rsA[half];
        const float csel = FIRST ? 0.f : cA[half];
        const int h0 = half << 5;
        SLD(0, h0); SLD(1, h0 + 1); SLD(2, h0 + 2);
        for (int c = h0; c < h0 + 32; c += 4) {
            SLD(3, c + 3);
            SCP(0);
            SLD(0, c + 4);
            SCP(1);
            SLD(1, c + 5);
            SCP(2);
            SLD(2, c + 6);
            SCP(3);
        }
    }
#undef SLD
#undef SCP

    // epilogue: skip + relu, in-place raw h update, LN partials
    float s1j[4] = {0.f, 0.f, 0.f, 0.f}, s2j[4] = {0.f, 0.f, 0.f, 0.f};
    #pragma unroll
    for (int ni = 0; ni < 2; ++ni) {
        const int col = n0 + (((wn << 1) + ni) << 4) + lo;
        const float cbv = cb[col];
        const float gv = lng[col], bv = lnb[col];
        #pragma unroll
        for (int j = 0; j < 4; ++j) {
            const int t = t0 + (wm << 4) + (hi << 2) + j;
            if (t <= 126) {
                const size_t off = (((size_t)(b * Ss + t)) << 10) + col;
                const float raw = hfS[off];
                float skip;
                if constexpr (FIRST) skip = raw;
                else skip = fmaf(fmaf(raw, rsE[j], -muE[j] * rsE[j]), gv, bv);
                const float av = (ni == 0) ? acc0[j] : acc1[j];
                const float pre = 0.1f * fmaxf(av + cbv, 0.f) + skip;
                hfD[off] = pre;
                hbD[off] = (bf16)pre;
                s1j[j] += pre; s2j[j] += pre * pre;
            }
        }
    }
    #pragma unroll
    for (int off = 1; off < 16; off <<= 1) {
        #pragma unroll
        for (int j = 0; j < 4; ++j) {
            s1j[j] += __shfl_xor(s1j[j], off);
            s2j[j] += __shfl_xor(s2j[j], off);
        }
    }
    if (lo == 0) {
        #pragma unroll
        for (int j = 0; j < 4; ++j) {
            ls[(wm << 4) + (hi << 2) + j][wn][0] = s1j[j];
            ls[(wm << 4) + (hi << 2) + j][wn][1] = s2j[j];
        }
    }
    __syncthreads();
    if (tid < 32) {
        const int t = t0 + tid;
        if (t <= 126) {
            const size_t base = (((size_t)(b * Ss + t)) << 4) + (bx << 1);
            prtW[base]     = ls[tid][0][0] + ls[tid][1][0] + ls[tid][2][0] + ls[tid][3][0];
            prtW[base + 1] = ls[tid][0][1] + ls[tid][1][1] + ls[tid][2][1] + ls[tid][3][1];
        }
    }
}

// ---------------------------------------------------------------------------
// Finalize outputState: os[b][m] = LN(hp_{(m+1)&1}[b][m+1]) using its stats.
// grid (126, 8), block 256 (4 cols each).
// ---------------------------------------------------------------------------
__global__ __launch_bounds__(256) void k_finish_os(
    const float* __restrict__ hpf0, const float* __restrict__ hpf1,
    const float* __restrict__ prt0, const float* __restrict__ prt1,
    const float* __restrict__ lng, const float* __restrict__ lnb,
    float* __restrict__ os)
{
    const int m = blockIdx.x, b = blockIdx.y, r = m + 1;
    const int p = r & 1;
    const float* hp = p ? hpf1 : hpf0;
    const float* pr = p ? prt1 : prt0;
    const float4* pp = reinterpret_cast<const float4*>(pr + (((size_t)(b * Ss + r)) << 4));
    float s1 = 0.f, s2 = 0.f;
    #pragma unroll
    for (int i = 0; i < 4; ++i) { float4 v = pp[i]; s1 += v.x + v.z; s2 += v.y + v.w; }
    const float mu = s1 * (1.f / Hh);
    const float rs = rsqrtf(s2 * (1.f / Hh) - mu * mu + 1e-5f);
    const int c4 = threadIdx.x << 2;
    const float4 raw = *reinterpret_cast<const float4*>(hp + (((size_t)(b * Ss + r)) << 10) + c4);
    const float4 g4 = *reinterpret_cast<const float4*>(&lng[c4]);
    const float4 b4 = *reinterpret_cast<const float4*>(&lnb[c4]);
    float4 o;
    o.x = fmaf((raw.x - mu) * rs, g4.x, b4.x);
    o.y = fmaf((raw.y - mu) * rs, g4.y, b4.y);
    o.z = fmaf((raw.z - mu) * rs, g4.z, b4.z);
    o.w = fmaf((raw.w - mu) * rs, g4.w, b4.w);
    *reinterpret_cast<float4*>(os + (((size_t)(b * Ss + m)) << 10) + c4) = o;
}

// Head LayerNorm in place (eps 1e-12) + optional bf16 mirror. grid 1024.
__global__ __launch_bounds__(256) void k_ln_rows2(
    float* __restrict__ buf, const float* __restrict__ g,
    const float* __restrict__ be, bf16* __restrict__ ybb)
{
    const int tid = threadIdx.x;
    float* rowp = buf + (size_t)blockIdx.x * Hh;
    float4 v = *reinterpret_cast<float4*>(&rowp[tid << 2]);
    float s1 = v.x + v.y + v.z + v.w;
    float s2 = v.x*v.x + v.y*v.y + v.z*v.z + v.w*v.w;
    #pragma unroll
    for (int off = 1; off < 64; off <<= 1) { s1 += __shfl_xor(s1, off); s2 += __shfl_xor(s2, off); }
    __shared__ float r1[4], r2[4];
    if ((tid & 63) == 0) { r1[tid >> 6] = s1; r2[tid >> 6] = s2; }
    __syncthreads();
    s1 = r1[0] + r1[1] + r1[2] + r1[3];
    s2 = r2[0] + r2[1] + r2[2] + r2[3];
    const float mu = s1 * (1.f / Hh);
    const float rs = rsqrtf(s2 * (1.f / Hh) - mu * mu + 1e-12f);
    const float4 g4 = *reinterpret_cast<const float4*>(&g[tid << 2]);
    const float4 b4 = *reinterpret_cast<const float4*>(&be[tid << 2]);
    float4 o;
    o.x = (v.x - mu) * rs * g4.x + b4.x;
    o.y = (v.y - mu) * rs * g4.y + b4.y;
    o.z = (v.z - mu) * rs * g4.z + b4.z;
    o.w = (v.w - mu) * rs * g4.w + b4.w;
    *reinterpret_cast<float4*>(&rowp[tid << 2]) = o;
    if (ybb) {
        v4bf ob; ob[0] = (bf16)o.x; ob[1] = (bf16)o.y; ob[2] = (bf16)o.z; ob[3] = (bf16)o.w;
        *reinterpret_cast<v4bf*>(&ybb[(size_t)blockIdx.x * Hh + (tid << 2)]) = ob;
    }
}

// ---------------------------------------------------------------------------
// Decoder bf16 MFMA (fast path): C[1024][32000] = ybb @ Wdec + bd.
// grid (250), block 512, __launch_bounds__(512,2) -> VGPR budget 256 so the
// pipeline actually fits in registers (R5-R10 ran at VGPR=64: serialized).
// Block owns a 128-col B-slice; loops 4 row-tiles (B L2-reuse, R8's FETCH
// drop); inner: A 2-deep / B 4-deep named-slot prefetch, guarded (no overrun).
// ---------------------------------------------------------------------------
__global__ __launch_bounds__(512, 2) void k_dec_mm(
    const bf16* __restrict__ A, const bf16* __restrict__ Wp,
    const float* __restrict__ bd, float* __restrict__ C)
{
    const int tid = threadIdx.x, l = tid & 63, w = tid >> 6;
    const int wr = w >> 1, wc = w & 1;
    const int n0 = (blockIdx.x << 7) + (wc << 6);
    const int sb = (blockIdx.x << 3) + (wc << 2);
    const bf16* pB = Wp + (((size_t)(sb << 6) + l) << 3);
    const int r4 = (l >> 4) << 2, cn = l & 15;

    v8bf a0[4], a1[4], b0[4], b1[4], b2[4], b3[4];

#define LA(S, c) do { _Pragma("unroll")                                       \
        for (int mi = 0; mi < 4; ++mi)                                        \
            S[mi] = *reinterpret_cast<const v8bf*>(                           \
                pA + (((size_t)mi << 4) << 10) + ((c) << 5)); } while (0)
#define LB(S, c) do { _Pragma("unroll")                                       \
        for (int ni = 0; ni < 4; ++ni)                                        \
            S[ni] = *reinterpret_cast<const v8bf*>(                           \
                pB + (size_t)(c) * 1024000 + ((ni) << 9)); } while (0)
#define MM(AS, BS) do { _Pragma("unroll")                                     \
        for (int mi = 0; mi < 4; ++mi)                                        \
            _Pragma("unroll")                                                 \
            for (int ni = 0; ni < 4; ++ni)                                    \
                acc[mi][ni] = __builtin_amdgcn_mfma_f32_16x16x32_bf16(        \
                    AS[mi], BS[ni], acc[mi][ni], 0, 0, 0); } while (0)

    for (int rt = 0; rt < 4; ++rt) {
        const int r0 = (rt << 8) + (wr << 6);
        const bf16* pA = A + (((size_t)(r0 + (l & 15))) << 10) + ((l >> 4) << 3);
        f32x4 acc[4][4] = {};

        LB(b0, 0); LB(b1, 1); LB(b2, 2); LA(a0, 0); LA(a1, 1);
        #pragma unroll
        for (int cc = 0; cc < 32; cc += 4) {
            LB(b3, cc + 3);                      MM(a0, b0);   // c = cc
            if (cc + 2 < 32) LA(a0, cc + 2);
            if (cc + 4 < 32) LB(b0, cc + 4);     MM(a1, b1);   // c = cc+1
            if (cc + 3 < 32) LA(a1, cc + 3);
            if (cc + 5 < 32) LB(b1, cc + 5);     MM(a0, b2);   // c = cc+2
            if (cc + 4 < 32) LA(a0, cc + 4);
            if (cc + 6 < 32) LB(b2, cc + 6);     MM(a1, b3);   // c = cc+3
            if (cc + 5 < 32) LA(a1, cc + 5);
        }

        #pragma unroll
        for (int mi = 0; mi < 4; ++mi) {
            #pragma unroll
            for (int ni = 0; ni < 4; ++ni) {
                const int col = n0 + (ni << 4) + cn;
                const float bj = bd[col];
                #pragma unroll
                for (int j = 0; j < 4; ++j) {
                    const int row = r0 + (mi << 4) + r4 + j;
                    C[(size_t)row * Vv + col] = acc[mi][ni][j] + bj;
                }
            }
        }
    }
#undef LA
#undef LB
#undef MM
}

// Decoder fp32 fallback (small-ws path). grid (500,16).
__global__ __launch_bounds__(256) void k_decoder(
    const float* __restrict__ A, const float* __restrict__ Wd,
    const float* __restrict__ bd, float* __restrict__ C)
{
    __shared__ float As[16][68];
    __shared__ float Bs[16][68];
    const int tid = threadIdx.x;
    const int tx = tid & 15, ty = tid >> 4;
    const int n0 = blockIdx.x << 6, r0 = blockIdx.y << 6;
    float acc[4][4] = {};
    for (int k0 = 0; k0 < Hh; k0 += 16) {
        __syncthreads();
        #pragma unroll
        for (int u = 0; u < 4; ++u) {
            int e = (u << 8) + tid;
            int r = e >> 4, kk = e & 15;
            As[kk][r] = A[(size_t)(r0 + r) * Hh + k0 + kk];
        }
        #pragma unroll
        for (int u = 0; u < 4; ++u) {
            int e = (u << 8) + tid;
            int kk = e >> 6, nn = e & 63;
            Bs[kk][nn] = Wd[(size_t)(k0 + kk) * Vv + n0 + nn];
        }
        __syncthreads();
        #pragma unroll
        for (int kk = 0; kk < 16; ++kk) {
            float a[4], wv[4];
            #pragma unroll
            for (int i = 0; i < 4; ++i) a[i] = As[kk][ty + (i << 4)];
            #pragma unroll
            for (int j = 0; j < 4; ++j) wv[j] = Bs[kk][tx + (j << 4)];
            #pragma unroll
            for (int i = 0; i < 4; ++i)
                #pragma unroll
                for (int j = 0; j < 4; ++j)
                    acc[i][j] = fmaf(a[i], wv[j], acc[i][j]);
        }
    }
    #pragma unroll
    for (int j = 0; j < 4; ++j) {
        const float bj = bd[n0 + tx + (j << 4)];
        #pragma unroll
        for (int i = 0; i < 4; ++i)
            C[(size_t)(r0 + ty + (i << 4)) * Vv + n0 + tx + (j << 4)] = acc[i][j] + bj;
    }
}

// ---------------------------------------------------------------------------
// CE loss.
// ---------------------------------------------------------------------------
__global__ __launch_bounds__(256) void k_loss_row(
    const float* __restrict__ logits, const int* __restrict__ labels,
    float* __restrict__ partial)
{
    const int row = blockIdx.x;
    const float* lr = logits + (size_t)row * Vv;
    float m = -3.4e38f, s = 0.f;
    for (int i = threadIdx.x; i < Vv; i += 256) {
        float v = lr[i];
        float nm = fmaxf(m, v);
        s = s * expf(m - nm) + expf(v - nm);
        m = nm;
    }
    #pragma unroll
    for (int off = 1; off < 64; off <<= 1) {
        float om = __shfl_xor(m, off);
        float osv = __shfl_xor(s, off);
        float nm = fmaxf(m, om);
        s = s * expf(m - nm) + osv * expf(om - nm);
        m = nm;
    }
    __shared__ float lm[4], lsum[4];
    const int wid = threadIdx.x >> 6;
    if ((threadIdx.x & 63) == 0) { lm[wid] = m; lsum[wid] = s; }
    __syncthreads();
    if (threadIdx.x == 0) {
        float M = lm[0], Sv = lsum[0];
        #pragma unroll
        for (int ww = 1; ww < 4; ++ww) {
            float nm = fmaxf(M, lm[ww]);
            Sv = Sv * expf(M - nm) + lsum[ww] * expf(lm[ww] - nm);
            M = nm;
        }
        partial[row] = (M + logf(Sv)) - lr[labels[row]];
    }
}

__global__ __launch_bounds__(256) void k_loss_final(
    const float* __restrict__ partial, float* __restrict__ out0)
{
    float s = partial[threadIdx.x] + partial[threadIdx.x + 256]
            + partial[threadIdx.x + 512] + partial[threadIdx.x + 768];
    #pragma unroll
    for (int off = 1; off < 64; off <<= 1) s += __shfl_xor(s, off);
    __shared__ float red[4];
    if ((threadIdx.x & 63) == 0) red[threadIdx.x >> 6] = s;
    __syncthreads();
    if (threadIdx.x == 0) out0[0] = (red[0] + red[1] + red[2] + red[3]) * (1.f / NROWS);
}

// ---------------------------------------------------------------------------
extern "C" void kernel_launch(void* const* d_in, const int* in_sizes, int n_in,
                              void* d_out, int out_size, void* d_ws, size_t ws_size,
                              hipStream_t stream)
{
    const int*   labels  = (const int*)d_in[0];
    const float* emb     = (const float*)d_in[1];
    const float* W_in    = (const float*)d_in[2];
    const float* b_in    = (const float*)d_in[3];
    const float* W_sani  = (const float*)d_in[4];
    const float* b_sani  = (const float*)d_in[5];
    const float* ln_g    = (const float*)d_in[6];
    const float* ln_b    = (const float*)d_in[7];
    const float* W_dense = (const float*)d_in[8];
    const float* b_dense = (const float*)d_in[9];
    const float* ln2_g   = (const float*)d_in[10];
    const float* ln2_b   = (const float*)d_in[11];
    const float* W_dec   = (const float*)d_in[12];
    const float* b_dec   = (const float*)d_in[13];
    float* out    = (float*)d_out;
    float* logits = out + 1;

    const size_t NH = (size_t)NROWS * Hh;                 // 1M elems
    const size_t WDP_ELEMS = (size_t)32 * 2000 * 64 * 8;  // 32.768M bf16

    // out-scratch (dead before logits are written):
    float* S     = out + 8;
    float* hpf0  = S;                         // raw h f32 ping
    float* hpf1  = S + NH;                    // raw h f32 pong
    float* os    = S + 2 * NH;                // outputState f32
    float* ybf   = S + 3 * NH;                // head dense out
    bf16*  Wp0   = (bf16*)(S + 4 * NH);       // sani packed plain
    bf16*  Wp1   = (bf16*)(S + 5 * NH);       // sani packed * ln_g
    bf16*  hpb0  = (bf16*)(S + 6 * NH);       // raw h bf16 ping
    bf16*  hpb1  = hpb0 + NH;                 // raw h bf16 pong
    float* prt0  = S + 7 * NH;                // stats ping  [8*128*16]
    float* prt1  = prt0 + 8 * Ss * 16;        // stats pong
    float* cbias = prt1 + 8 * Ss * 16;        // folded bias [1024]

    const bool fast = ws_size >= WDP_ELEMS * 2 + NH * 2 + 8192;
    bf16 *Wdp = nullptr, *ybb = nullptr;
    float *yb, *pt;
    float* wsf = (float*)d_ws;
    if (fast) {
        Wdp = (bf16*)d_ws;
        ybb = Wdp + WDP_ELEMS;
        pt  = (float*)(ybb + NH);
        yb  = ybf;
    } else {
        yb = wsf;
        pt = wsf + NH;
    }

    k_pack2<<<dim3(64, 4), 256, 0, stream>>>(W_sani, Wp0, Hh, nullptr);
    k_pack2<<<dim3(64, 4), 256, 0, stream>>>(W_sani, Wp1, Hh, ln_g);
    k_cbias<<<4, 256, 0, stream>>>(W_sani, b_sani, ln_b, cbias);
    if (fast)
        k_pack2<<<dim3(32, 125), 256, 0, stream>>>(W_dec, Wdp, Vv, nullptr);

    hipMemsetAsync(os, 0, NH * sizeof(float), stream);   // rows 126/127 stay 0
    k_gemm1024<0><<<dim3(4, 64), 256, 0, stream>>>(labels, emb, W_in, b_in, hpf0, hpb0);

    for (int m = 0; m < Ss - 2; ++m) {
        const int src = m & 1;
        const int nt  = 126 - m;                 // rows m+1..126 (row 127 dead)
        const dim3 grid(8, (nt + 31) >> 5, Bb);
        const bf16*  hbA = src ? hpb1 : hpb0;
        const float* hfS = src ? hpf1 : hpf0;
        float* hfD = src ? hpf0 : hpf1;
        bf16*  hbD = src ? hpb0 : hpb1;
        const float* pR = src ? prt1 : prt0;
        float*       pW = src ? prt0 : prt1;
        if (m == 0)
            k_scan_fused6<1><<<grid, 512, 0, stream>>>(hbA, hfS, hfD, hbD,
                Wp0, b_sani, pR, pW, ln_g, ln_b, m);
        else
            k_scan_fused6<0><<<grid, 512, 0, stream>>>(hbA, hfS, hfD, hbD,
                Wp1, cbias, pR, pW, ln_g, ln_b, m);
        k_nop<<<1, 64, 0, stream>>>();   // boundary-cost probe: +126 launches
    }

    k_finish_os<<<dim3(126, Bb), 256, 0, stream>>>(hpf0, hpf1, prt0, prt1,
                                                   ln_g, ln_b, os);

    k_gemm1024<1><<<dim3(4, 64), 256, 0, stream>>>(nullptr, os, W_dense, b_dense, yb, nullptr);
    k_ln_rows2<<<NROWS, 256, 0, stream>>>(yb, ln2_g, ln2_b, ybb);
    if (fast)
        k_dec_mm<<<dim3(250), 512, 0, stream>>>(ybb, Wdp, b_dec, logits);
    else
        k_decoder<<<dim3(Vv / 64, NROWS / 64), 256, 0, stream>>>(yb, W_dec, b_dec, logits);
    k_loss_row<<<NROWS, 256, 0, stream>>>(logits, labels, pt);
    k_loss_final<<<1, 256, 0, stream>>>(pt, out);
}

// Round 12
// 3973.592 us; speedup vs baseline: 1.1324x; 1.1324x over previous
//
#include <hip/hip_runtime.h>
#include <hip/hip_bf16.h>

#define Bb 8
#define Ss 128
#define Hh 1024
#define Vv 32000
#define NROWS (Bb*Ss)   // 1024

typedef __bf16 bf16;
typedef __bf16 v8bf __attribute__((ext_vector_type(8)));
typedef __bf16 v4bf __attribute__((ext_vector_type(4)));
typedef float  f32x4 __attribute__((ext_vector_type(4)));

#define GLOAD_LDS16(g, l) __builtin_amdgcn_global_load_lds(                   \
    (const __attribute__((address_space(1))) unsigned int*)(const void*)(g),  \
    (__attribute__((address_space(3))) unsigned int*)(l), 16, 0, 0)

// ---------------------------------------------------------------------------
// Pack row-major f32 W[K][N] -> frag-linear bf16 (validated layout):
//   Wp[((c*(N/16) + s)*64 + l)*8 + e] = W[32c + 8*(l>>4) + e][16s + (l&15)]
// optionally scaling row k by gscale[k & 1023] (LN-gamma fold).
// grid (K/32, N/256), block 256.
// ---------------------------------------------------------------------------
__global__ __launch_bounds__(256) void k_pack2(
    const float* __restrict__ W, bf16* __restrict__ Wp, int N,
    const float* __restrict__ gscale)
{
    __shared__ bf16 lt[32][258];
    const int c = blockIdx.x, n0 = blockIdx.y << 8;
    const int Ns = N >> 4, s0 = n0 >> 4;
    const int tid = threadIdx.x;
    #pragma unroll
    for (int i = 0; i < 8; ++i) {
        int q = (i << 8) + tid;          // 2048 float4 slots = 32 rows x 64
        int kk = q >> 6, nq = q & 63;
        float gs = gscale ? gscale[((c << 5) + kk) & 1023] : 1.0f;
        float4 v = *reinterpret_cast<const float4*>(
            &W[(size_t)((c << 5) + kk) * N + n0 + (nq << 2)]);
        lt[kk][(nq << 2) + 0] = (bf16)(v.x * gs);
        lt[kk][(nq << 2) + 1] = (bf16)(v.y * gs);
        lt[kk][(nq << 2) + 2] = (bf16)(v.z * gs);
        lt[kk][(nq << 2) + 3] = (bf16)(v.w * gs);
    }
    __syncthreads();
    #pragma unroll
    for (int u = 0; u < 4; ++u) {
        int p = (u << 8) + tid;          // 1024 (s,l) pairs
        int s = p >> 6, ll = p & 63;
        v8bf pk;
        #pragma unroll
        for (int e = 0; e < 8; ++e)
            pk[e] = lt[((ll >> 4) << 3) + e][(s << 4) + (ll & 15)];
        *reinterpret_cast<v8bf*>(
            &Wp[((((size_t)c * Ns + s0 + s) << 6) + ll) << 3]) = pk;
    }
}

// cbias[n] = b_sani[n] + sum_k W_sani[k][n] * lnb[k & 1023]. grid 4 x 256.
__global__ __launch_bounds__(256) void k_cbias(
    const float* __restrict__ W, const float* __restrict__ bs,
    const float* __restrict__ lnb, float* __restrict__ cbias)
{
    const int col = blockIdx.x * 256 + threadIdx.x;
    float s = bs[col];
    #pragma unroll 8
    for (int k = 0; k < 2 * Hh; ++k)
        s = fmaf(W[(size_t)k * Hh + col], lnb[k & (Hh - 1)], s);
    cbias[col] = s;
}

// ---------------------------------------------------------------------------
// Generic rows x 1024 GEMM, K=1024 (fp32).
// MODE 0: A-row = emb[labels[row]] (gather), relu, + bf16 mirror out.
// MODE 1: A-row = A[row] (direct), exact gelu.
// ---------------------------------------------------------------------------
template<int MODE>
__global__ __launch_bounds__(256) void k_gemm1024(
    const int* __restrict__ labels, const float* __restrict__ A,
    const float* __restrict__ W, const float* __restrict__ bias,
    float* __restrict__ out, bf16* __restrict__ outb)
{
    __shared__ float Als[16][32];
    const int tid  = threadIdx.x;
    const int jj   = (blockIdx.x << 8) + ((tid & 63) << 2);
    const int rg   = tid >> 6;
    const int row0 = blockIdx.y << 4;
    float acc[4][4] = {};
    for (int k0 = 0; k0 < Hh; k0 += 32) {
        __syncthreads();
        #pragma unroll
        for (int u = 0; u < 2; ++u) {
            int i = (u << 8) + tid;
            int r = i >> 5, kk = i & 31;
            int row = row0 + r;
            size_t base = (MODE == 0) ? (size_t)labels[row] * Hh : (size_t)row * Hh;
            Als[r][kk] = A[base + k0 + kk];
        }
        __syncthreads();
        #pragma unroll 8
        for (int kk = 0; kk < 32; ++kk) {
            const float4 w4 = *reinterpret_cast<const float4*>(&W[(size_t)(k0 + kk) * Hh + jj]);
            #pragma unroll
            for (int i = 0; i < 4; ++i) {
                float a = Als[(rg << 2) + i][kk];
                acc[i][0] = fmaf(a, w4.x, acc[i][0]);
                acc[i][1] = fmaf(a, w4.y, acc[i][1]);
                acc[i][2] = fmaf(a, w4.z, acc[i][2]);
                acc[i][3] = fmaf(a, w4.w, acc[i][3]);
            }
        }
    }
    const float4 b4 = *reinterpret_cast<const float4*>(&bias[jj]);
    #pragma unroll
    for (int i = 0; i < 4; ++i) {
        int row = row0 + (rg << 2) + i;
        float v[4] = {acc[i][0] + b4.x, acc[i][1] + b4.y, acc[i][2] + b4.z, acc[i][3] + b4.w};
        float o[4];
        #pragma unroll
        for (int j = 0; j < 4; ++j) {
            if (MODE == 0) o[j] = fmaxf(v[j], 0.f);
            else           o[j] = 0.5f * v[j] * (1.f + erff(v[j] * 0.70710678f));
        }
        *reinterpret_cast<float4*>(&out[(size_t)row * Hh + jj]) =
            make_float4(o[0], o[1], o[2], o[3]);
        if (MODE == 0) {
            v4bf ob; ob[0] = (bf16)o[0]; ob[1] = (bf16)o[1];
            ob[2] = (bf16)o[2]; ob[3] = (bf16)o[3];
            *reinterpret_cast<v4bf*>(&outb[(size_t)row * Hh + jj]) = ob;
        }
    }
}

// ---------------------------------------------------------------------------
// Fused scan step m (v7 = R6 structure, but B staged through double-buffered
// LDS via global_load_lds width-16 — removes ~2/3 of vector-path bytes).
// Stage = 4 K-chunks (32KB); per chunk the block's B slice is one contiguous
// 8KB segment of frag-linear Wp -> LDS stays frag-linear; ds_read_b128
// conflict-free (64 lanes x 16B contiguous).
// Block 32r x 128c, 512 thr, 8 waves (wm=w>>2 rows, wn=w&3 cols), wave
// 16r x 32c. grid (8, ceil(nt/32), 8). C/D map col=l&15, row=4*(l>>4)+j.
// ---------------------------------------------------------------------------
template<int FIRST>
__global__ __launch_bounds__(512) void k_scan_fused7(
    const bf16* __restrict__ hbA, const float* __restrict__ hfS,
    float* __restrict__ hfD, bf16* __restrict__ hbD,
    const bf16* __restrict__ Wp, const float* __restrict__ cb,
    const float* __restrict__ prtR, float* __restrict__ prtW,
    const float* __restrict__ lng, const float* __restrict__ lnb, int m)
{
    __shared__ __align__(16) char ldsB[2][32768];
    __shared__ float musig[33][2];   // (mu, rs) for rows t0-1 .. t0+31
    __shared__ float ls[32][4][2];
    const int tid = threadIdx.x, l = tid & 63, w = tid >> 6;
    const int wm = w >> 2, wn = w & 3;
    const int lo = l & 15, hi = l >> 4;
    const int bx = blockIdx.x;                 // 0..7 (128-col blocks)
    const int n0 = bx << 7;
    const int t0 = m + 1 + (blockIdx.y << 5);
    const int b  = blockIdx.z;

    if constexpr (!FIRST) {
        if (tid < 264) {
            const int idx = tid >> 3, pr = tid & 7;
            int r = t0 - 1 + idx; if (r > 126) r = 126;
            const float2 v = *reinterpret_cast<const float2*>(
                prtR + (((size_t)(b * Ss + r)) << 4) + (pr << 1));
            float s1 = v.x, s2 = v.y;
            #pragma unroll
            for (int off = 1; off < 8; off <<= 1) {
                s1 += __shfl_xor(s1, off);
                s2 += __shfl_xor(s2, off);
            }
            if (pr == 0) {
                const float mu = s1 * (1.f / Hh);
                const float rs = rsqrtf(s2 * (1.f / Hh) - mu * mu + 1e-5f);
                musig[idx][0] = mu; musig[idx][1] = rs;
            }
        }
    }

    int tA = t0 + (wm << 4) + lo; if (tA > 126) tA = 126;
    const bf16* pA = hbA + (((size_t)(b * Ss + tA - 1)) << 10) + (hi << 3);
    // B staging source: chunk c slice = Wp + c*32768 + bx*4096 elems, 8KB.
    const bf16* pBsrc = Wp + ((size_t)bx << 12) + ((size_t)tid << 3);
    const int ldsWoff = (tid >> 6) << 10;      // wave-uniform 1KB slot
    const int sl0 = wn << 1;                   // wave's local subtiles sl0, sl0+1

#define STAGE(buf, st) do {                                                   \
        _Pragma("unroll")                                                     \
        for (int q_ = 0; q_ < 4; ++q_)                                        \
            GLOAD_LDS16(pBsrc + (((size_t)((st) * 4 + q_)) << 15),            \
                        &ldsB[buf][(q_ << 13) + ldsWoff]);                    \
    } while (0)

    STAGE(0, 0);
    __syncthreads();   // also covers musig writes

    float rsA[2] = {1.f, 1.f}, cA[2] = {0.f, 0.f};
    float muE[4] = {0.f, 0.f, 0.f, 0.f}, rsE[4] = {1.f, 1.f, 1.f, 1.f};
    if constexpr (!FIRST) {
        const int ia = tA - t0;
        #pragma unroll
        for (int q = 0; q < 2; ++q) {
            const float mu = musig[ia + q][0], rs = musig[ia + q][1];
            rsA[q] = rs; cA[q] = -mu * rs;
        }
        #pragma unroll
        for (int j = 0; j < 4; ++j) {
            const int ie = (wm << 4) + (hi << 2) + j + 1;   // always <= 32
            muE[j] = musig[ie][0]; rsE[j] = musig[ie][1];
        }
    }

    f32x4 acc0 = {}, acc1 = {};
    int buf = 0;
    for (int st = 0; st < 16; ++st) {
        if (st < 15) STAGE(buf ^ 1, st + 1);
        __syncthreads();                       // waitcnt drains DMA loads
        const float rsel = FIRST ? 1.f : rsA[st >> 3];
        const float csel = FIRST ? 0.f : cA[st >> 3];
        #pragma unroll
        for (int q = 0; q < 4; ++q) {
            const int c = (st << 2) + q;
            const uint4 ar = *reinterpret_cast<const uint4*>(pA + (c << 5));
            v8bf a;
            if constexpr (FIRST) {
                a = *reinterpret_cast<const v8bf*>(&ar);
            } else {
                const unsigned u[4] = {ar.x, ar.y, ar.z, ar.w};
                #pragma unroll
                for (int i = 0; i < 4; ++i) {
                    float xl = __uint_as_float(u[i] << 16);
                    float xh = __uint_as_float(u[i] & 0xffff0000u);
                    a[2 * i]     = (bf16)fmaf(xl, rsel, csel);
                    a[2 * i + 1] = (bf16)fmaf(xh, rsel, csel);
                }
            }
            const v8bf b0 = *reinterpret_cast<const v8bf*>(
                &ldsB[buf][(q << 13) + (sl0 << 10) + (l << 4)]);
            const v8bf b1 = *reinterpret_cast<const v8bf*>(
                &ldsB[buf][(q << 13) + ((sl0 + 1) << 10) + (l << 4)]);
            acc0 = __builtin_amdgcn_mfma_f32_16x16x32_bf16(a, b0, acc0, 0, 0, 0);
            acc1 = __builtin_amdgcn_mfma_f32_16x16x32_bf16(a, b1, acc1, 0, 0, 0);
        }
        __syncthreads();                       // protect buf before overwrite
        buf ^= 1;
    }
#undef STAGE

    // epilogue: skip + relu, in-place raw h update, LN partials
    float s1j[4] = {0.f, 0.f, 0.f, 0.f}, s2j[4] = {0.f, 0.f, 0.f, 0.f};
    #pragma unroll
    for (int ni = 0; ni < 2; ++ni) {
        const int col = n0 + (((wn << 1) + ni) << 4) + lo;
        const float cbv = cb[col];
        const float gv = lng[col], bv = lnb[col];
        #pragma unroll
        for (int j = 0; j < 4; ++j) {
            const int t = t0 + (wm << 4) + (hi << 2) + j;
            if (t <= 126) {
                const size_t off = (((size_t)(b * Ss + t)) << 10) + col;
                const float raw = hfS[off];
                float skip;
                if constexpr (FIRST) skip = raw;
                else skip = fmaf(fmaf(raw, rsE[j], -muE[j] * rsE[j]), gv, bv);
                const float av = (ni == 0) ? acc0[j] : acc1[j];
                const float pre = 0.1f * fmaxf(av + cbv, 0.f) + skip;
                hfD[off] = pre;
                hbD[off] = (bf16)pre;
                s1j[j] += pre; s2j[j] += pre * pre;
            }
        }
    }
    #pragma unroll
    for (int off = 1; off < 16; off <<= 1) {
        #pragma unroll
        for (int j = 0; j < 4; ++j) {
            s1j[j] += __shfl_xor(s1j[j], off);
            s2j[j] += __shfl_xor(s2j[j], off);
        }
    }
    if (lo == 0) {
        #pragma unroll
        for (int j = 0; j < 4; ++j) {
            ls[(wm << 4) + (hi << 2) + j][wn][0] = s1j[j];
            ls[(wm << 4) + (hi << 2) + j][wn][1] = s2j[j];
        }
    }
    __syncthreads();
    if (tid < 32) {
        const int t = t0 + tid;
        if (t <= 126) {
            const size_t base = (((size_t)(b * Ss + t)) << 4) + (bx << 1);
            prtW[base]     = ls[tid][0][0] + ls[tid][1][0] + ls[tid][2][0] + ls[tid][3][0];
            prtW[base + 1] = ls[tid][0][1] + ls[tid][1][1] + ls[tid][2][1] + ls[tid][3][1];
        }
    }
}

// ---------------------------------------------------------------------------
// Finalize outputState: os[b][m] = LN(hp_{(m+1)&1}[b][m+1]) using its stats.
// grid (126, 8), block 256 (4 cols each).
// ---------------------------------------------------------------------------
__global__ __launch_bounds__(256) void k_finish_os(
    const float* __restrict__ hpf0, const float* __restrict__ hpf1,
    const float* __restrict__ prt0, const float* __restrict__ prt1,
    const float* __restrict__ lng, const float* __restrict__ lnb,
    float* __restrict__ os)
{
    const int m = blockIdx.x, b = blockIdx.y, r = m + 1;
    const int p = r & 1;
    const float* hp = p ? hpf1 : hpf0;
    const float* pr = p ? prt1 : prt0;
    const float4* pp = reinterpret_cast<const float4*>(pr + (((size_t)(b * Ss + r)) << 4));
    float s1 = 0.f, s2 = 0.f;
    #pragma unroll
    for (int i = 0; i < 4; ++i) { float4 v = pp[i]; s1 += v.x + v.z; s2 += v.y + v.w; }
    const float mu = s1 * (1.f / Hh);
    const float rs = rsqrtf(s2 * (1.f / Hh) - mu * mu + 1e-5f);
    const int c4 = threadIdx.x << 2;
    const float4 raw = *reinterpret_cast<const float4*>(hp + (((size_t)(b * Ss + r)) << 10) + c4);
    const float4 g4 = *reinterpret_cast<const float4*>(&lng[c4]);
    const float4 b4 = *reinterpret_cast<const float4*>(&lnb[c4]);
    float4 o;
    o.x = fmaf((raw.x - mu) * rs, g4.x, b4.x);
    o.y = fmaf((raw.y - mu) * rs, g4.y, b4.y);
    o.z = fmaf((raw.z - mu) * rs, g4.z, b4.z);
    o.w = fmaf((raw.w - mu) * rs, g4.w, b4.w);
    *reinterpret_cast<float4*>(os + (((size_t)(b * Ss + m)) << 10) + c4) = o;
}

// Head LayerNorm in place (eps 1e-12) + optional bf16 mirror. grid 1024.
__global__ __launch_bounds__(256) void k_ln_rows2(
    float* __restrict__ buf, const float* __restrict__ g,
    const float* __restrict__ be, bf16* __restrict__ ybb)
{
    const int tid = threadIdx.x;
    float* rowp = buf + (size_t)blockIdx.x * Hh;
    float4 v = *reinterpret_cast<float4*>(&rowp[tid << 2]);
    float s1 = v.x + v.y + v.z + v.w;
    float s2 = v.x*v.x + v.y*v.y + v.z*v.z + v.w*v.w;
    #pragma unroll
    for (int off = 1; off < 64; off <<= 1) { s1 += __shfl_xor(s1, off); s2 += __shfl_xor(s2, off); }
    __shared__ float r1[4], r2[4];
    if ((tid & 63) == 0) { r1[tid >> 6] = s1; r2[tid >> 6] = s2; }
    __syncthreads();
    s1 = r1[0] + r1[1] + r1[2] + r1[3];
    s2 = r2[0] + r2[1] + r2[2] + r2[3];
    const float mu = s1 * (1.f / Hh);
    const float rs = rsqrtf(s2 * (1.f / Hh) - mu * mu + 1e-12f);
    const float4 g4 = *reinterpret_cast<const float4*>(&g[tid << 2]);
    const float4 b4 = *reinterpret_cast<const float4*>(&be[tid << 2]);
    float4 o;
    o.x = (v.x - mu) * rs * g4.x + b4.x;
    o.y = (v.y - mu) * rs * g4.y + b4.y;
    o.z = (v.z - mu) * rs * g4.z + b4.z;
    o.w = (v.w - mu) * rs * g4.w + b4.w;
    *reinterpret_cast<float4*>(&rowp[tid << 2]) = o;
    if (ybb) {
        v4bf ob; ob[0] = (bf16)o.x; ob[1] = (bf16)o.y; ob[2] = (bf16)o.z; ob[3] = (bf16)o.w;
        *reinterpret_cast<v4bf*>(&ybb[(size_t)blockIdx.x * Hh + (tid << 2)]) = ob;
    }
}

// ---------------------------------------------------------------------------
// Decoder bf16 MFMA (fast path, R10 version): C = ybb @ Wdec + bd.
// grid (250, 4), block 512. Register double-buffered frags, no LDS/barriers.
// ---------------------------------------------------------------------------
__global__ __launch_bounds__(512) void k_dec_mm(
    const bf16* __restrict__ A, const bf16* __restrict__ Wp,
    const float* __restrict__ bd, float* __restrict__ C)
{
    const int tid = threadIdx.x, l = tid & 63, w = tid >> 6;
    const int wr = w >> 1, wc = w & 1;
    const int n0 = (blockIdx.x << 7) + (wc << 6);
    const int r0 = (blockIdx.y << 8) + (wr << 6);
    const bf16* pA = A + (((size_t)(r0 + (l & 15))) << 10) + ((l >> 4) << 3);
    const int sb = (blockIdx.x << 3) + (wc << 2);
    const bf16* pB = Wp + (((size_t)(sb << 6) + l) << 3);

    f32x4 acc[4][4] = {};
    v8bf afA[4], bfA[4], afB[4], bfB[4];

#define LOADSET(AF, BF, c) do {                                               \
        _Pragma("unroll")                                                     \
        for (int mi = 0; mi < 4; ++mi)                                        \
            AF[mi] = *reinterpret_cast<const v8bf*>(                          \
                pA + (((size_t)mi << 4) << 10) + ((c) << 5));                 \
        _Pragma("unroll")                                                     \
        for (int ni = 0; ni < 4; ++ni)                                        \
            BF[ni] = *reinterpret_cast<const v8bf*>(                          \
                pB + (size_t)(c) * 1024000 + (ni << 9));                      \
    } while (0)
#define MFMASET(AF, BF) do {                                                  \
        _Pragma("unroll")                                                     \
        for (int mi = 0; mi < 4; ++mi)                                        \
            _Pragma("unroll")                                                 \
            for (int ni = 0; ni < 4; ++ni)                                    \
                acc[mi][ni] = __builtin_amdgcn_mfma_f32_16x16x32_bf16(        \
                    AF[mi], BF[ni], acc[mi][ni], 0, 0, 0);                    \
    } while (0)

    LOADSET(afA, bfA, 0);
    for (int c = 0; c < 32; c += 2) {
        LOADSET(afB, bfB, c + 1);
        MFMASET(afA, bfA);
        if (c + 2 < 32) LOADSET(afA, bfA, c + 2);
        MFMASET(afB, bfB);
    }
#undef LOADSET
#undef MFMASET

    const int r4 = (l >> 4) << 2, cn = l & 15;
    #pragma unroll
    for (int mi = 0; mi < 4; ++mi) {
        #pragma unroll
        for (int ni = 0; ni < 4; ++ni) {
            const int col = n0 + (ni << 4) + cn;
            const float bj = bd[col];
            #pragma unroll
            for (int j = 0; j < 4; ++j) {
                const int row = r0 + (mi << 4) + r4 + j;
                C[(size_t)row * Vv + col] = acc[mi][ni][j] + bj;
            }
        }
    }
}

// Decoder fp32 fallback (small-ws path). grid (500,16).
__global__ __launch_bounds__(256) void k_decoder(
    const float* __restrict__ A, const float* __restrict__ Wd,
    const float* __restrict__ bd, float* __restrict__ C)
{
    __shared__ float As[16][68];
    __shared__ float Bs[16][68];
    const int tid = threadIdx.x;
    const int tx = tid & 15, ty = tid >> 4;
    const int n0 = blockIdx.x << 6, r0 = blockIdx.y << 6;
    float acc[4][4] = {};
    for (int k0 = 0; k0 < Hh; k0 += 16) {
        __syncthreads();
        #pragma unroll
        for (int u = 0; u < 4; ++u) {
            int e = (u << 8) + tid;
            int r = e >> 4, kk = e & 15;
            As[kk][r] = A[(size_t)(r0 + r) * Hh + k0 + kk];
        }
        #pragma unroll
        for (int u = 0; u < 4; ++u) {
            int e = (u << 8) + tid;
            int kk = e >> 6, nn = e & 63;
            Bs[kk][nn] = Wd[(size_t)(k0 + kk) * Vv + n0 + nn];
        }
        __syncthreads();
        #pragma unroll
        for (int kk = 0; kk < 16; ++kk) {
            float a[4], wv[4];
            #pragma unroll
            for (int i = 0; i < 4; ++i) a[i] = As[kk][ty + (i << 4)];
            #pragma unroll
            for (int j = 0; j < 4; ++j) wv[j] = Bs[kk][tx + (j << 4)];
            #pragma unroll
            for (int i = 0; i < 4; ++i)
                #pragma unroll
                for (int j = 0; j < 4; ++j)
                    acc[i][j] = fmaf(a[i], wv[j], acc[i][j]);
        }
    }
    #pragma unroll
    for (int j = 0; j < 4; ++j) {
        const float bj = bd[n0 + tx + (j << 4)];
        #pragma unroll
        for (int i = 0; i < 4; ++i)
            C[(size_t)(r0 + ty + (i << 4)) * Vv + n0 + tx + (j << 4)] = acc[i][j] + bj;
    }
}

// ---------------------------------------------------------------------------
// CE loss.
// ---------------------------------------------------------------------------
__global__ __launch_bounds__(256) void k_loss_row(
    const float* __restrict__ logits, const int* __restrict__ labels,
    float* __restrict__ partial)
{
    const int row = blockIdx.x;
    const float* lr = logits + (size_t)row * Vv;
    float m = -3.4e38f, s = 0.f;
    for (int i = threadIdx.x; i < Vv; i += 256) {
        float v = lr[i];
        float nm = fmaxf(m, v);
        s = s * expf(m - nm) + expf(v - nm);
        m = nm;
    }
    #pragma unroll
    for (int off = 1; off < 64; off <<= 1) {
        float om = __shfl_xor(m, off);
        float osv = __shfl_xor(s, off);
        float nm = fmaxf(m, om);
        s = s * expf(m - nm) + osv * expf(om - nm);
        m = nm;
    }
    __shared__ float lm[4], lsum[4];
    const int wid = threadIdx.x >> 6;
    if ((threadIdx.x & 63) == 0) { lm[wid] = m; lsum[wid] = s; }
    __syncthreads();
    if (threadIdx.x == 0) {
        float M = lm[0], Sv = lsum[0];
        #pragma unroll
        for (int ww = 1; ww < 4; ++ww) {
            float nm = fmaxf(M, lm[ww]);
            Sv = Sv * expf(M - nm) + lsum[ww] * expf(lm[ww] - nm);
            M = nm;
        }
        partial[row] = (M + logf(Sv)) - lr[labels[row]];
    }
}

__global__ __launch_bounds__(256) void k_loss_final(
    const float* __restrict__ partial, float* __restrict__ out0)
{
    float s = partial[threadIdx.x] + partial[threadIdx.x + 256]
            + partial[threadIdx.x + 512] + partial[threadIdx.x + 768];
    #pragma unroll
    for (int off = 1; off < 64; off <<= 1) s += __shfl_xor(s, off);
    __shared__ float red[4];
    if ((threadIdx.x & 63) == 0) red[threadIdx.x >> 6] = s;
    __syncthreads();
    if (threadIdx.x == 0) out0[0] = (red[0] + red[1] + red[2] + red[3]) * (1.f / NROWS);
}

// ---------------------------------------------------------------------------
extern "C" void kernel_launch(void* const* d_in, const int* in_sizes, int n_in,
                              void* d_out, int out_size, void* d_ws, size_t ws_size,
                              hipStream_t stream)
{
    const int*   labels  = (const int*)d_in[0];
    const float* emb     = (const float*)d_in[1];
    const float* W_in    = (const float*)d_in[2];
    const float* b_in    = (const float*)d_in[3];
    const float* W_sani  = (const float*)d_in[4];
    const float* b_sani  = (const float*)d_in[5];
    const float* ln_g    = (const float*)d_in[6];
    const float* ln_b    = (const float*)d_in[7];
    const float* W_dense = (const float*)d_in[8];
    const float* b_dense = (const float*)d_in[9];
    const float* ln2_g   = (const float*)d_in[10];
    const float* ln2_b   = (const float*)d_in[11];
    const float* W_dec   = (const float*)d_in[12];
    const float* b_dec   = (const float*)d_in[13];
    float* out    = (float*)d_out;
    float* logits = out + 1;

    const size_t NH = (size_t)NROWS * Hh;                 // 1M elems
    const size_t WDP_ELEMS = (size_t)32 * 2000 * 64 * 8;  // 32.768M bf16

    // out-scratch (dead before logits are written):
    float* S     = out + 8;
    float* hpf0  = S;                         // raw h f32 ping
    float* hpf1  = S + NH;                    // raw h f32 pong
    float* os    = S + 2 * NH;                // outputState f32
    float* ybf   = S + 3 * NH;                // head dense out
    bf16*  Wp0   = (bf16*)(S + 4 * NH);       // sani packed plain
    bf16*  Wp1   = (bf16*)(S + 5 * NH);       // sani packed * ln_g
    bf16*  hpb0  = (bf16*)(S + 6 * NH);       // raw h bf16 ping
    bf16*  hpb1  = hpb0 + NH;                 // raw h bf16 pong
    float* prt0  = S + 7 * NH;                // stats ping  [8*128*16]
    float* prt1  = prt0 + 8 * Ss * 16;        // stats pong
    float* cbias = prt1 + 8 * Ss * 16;        // folded bias [1024]

    const bool fast = ws_size >= WDP_ELEMS * 2 + NH * 2 + 8192;
    bf16 *Wdp = nullptr, *ybb = nullptr;
    float *yb, *pt;
    float* wsf = (float*)d_ws;
    if (fast) {
        Wdp = (bf16*)d_ws;
        ybb = Wdp + WDP_ELEMS;
        pt  = (float*)(ybb + NH);
        yb  = ybf;
    } else {
        yb = wsf;
        pt = wsf + NH;
    }

    k_pack2<<<dim3(64, 4), 256, 0, stream>>>(W_sani, Wp0, Hh, nullptr);
    k_pack2<<<dim3(64, 4), 256, 0, stream>>>(W_sani, Wp1, Hh, ln_g);
    k_cbias<<<4, 256, 0, stream>>>(W_sani, b_sani, ln_b, cbias);
    if (fast)
        k_pack2<<<dim3(32, 125), 256, 0, stream>>>(W_dec, Wdp, Vv, nullptr);

    hipMemsetAsync(os, 0, NH * sizeof(float), stream);   // rows 126/127 stay 0
    k_gemm1024<0><<<dim3(4, 64), 256, 0, stream>>>(labels, emb, W_in, b_in, hpf0, hpb0);

    for (int m = 0; m < Ss - 2; ++m) {
        const int src = m & 1;
        const int nt  = 126 - m;                 // rows m+1..126 (row 127 dead)
        const dim3 grid(8, (nt + 31) >> 5, Bb);
        const bf16*  hbA = src ? hpb1 : hpb0;
        const float* hfS = src ? hpf1 : hpf0;
        float* hfD = src ? hpf0 : hpf1;
        bf16*  hbD = src ? hpb0 : hpb1;
        const float* pR = src ? prt1 : prt0;
        float*       pW = src ? prt0 : prt1;
        if (m == 0)
            k_scan_fused7<1><<<grid, 512, 0, stream>>>(hbA, hfS, hfD, hbD,
                Wp0, b_sani, pR, pW, ln_g, ln_b, m);
        else
            k_scan_fused7<0><<<grid, 512, 0, stream>>>(hbA, hfS, hfD, hbD,
                Wp1, cbias, pR, pW, ln_g, ln_b, m);
    }

    k_finish_os<<<dim3(126, Bb), 256, 0, stream>>>(hpf0, hpf1, prt0, prt1,
                                                   ln_g, ln_b, os);

    k_gemm1024<1><<<dim3(4, 64), 256, 0, stream>>>(nullptr, os, W_dense, b_dense, yb, nullptr);
    k_ln_rows2<<<NROWS, 256, 0, stream>>>(yb, ln2_g, ln2_b, ybb);
    if (fast)
        k_dec_mm<<<dim3(250, 4), 512, 0, stream>>>(ybb, Wdp, b_dec, logits);
    else
        k_decoder<<<dim3(Vv / 64, NROWS / 64), 256, 0, stream>>>(yb, W_dec, b_dec, logits);
    k_loss_row<<<NROWS, 256, 0, stream>>>(logits, labels, pt);
    k_loss_final<<<1, 256, 0, stream>>>(pt, out);
}